// Round 3
// baseline (1354.575 us; speedup 1.0000x reference)
//
#include <hip/hip_runtime.h>
#include <math.h>

typedef unsigned short u16;
typedef __attribute__((ext_vector_type(8))) short short8;
typedef __attribute__((ext_vector_type(4))) float f32x4;

#define AS1 __attribute__((address_space(1)))
#define AS3 __attribute__((address_space(3)))

__device__ __forceinline__ void gload_lds16(const u16* g, u16* l) {
  __builtin_amdgcn_global_load_lds((AS1 void*)g, (AS3 void*)l, 16, 0, 0);
}

__device__ __forceinline__ float bf2f(u16 u) {
  union { unsigned i; float f; } c; c.i = ((unsigned)u) << 16; return c.f;
}
__device__ __forceinline__ u16 f2bf(float f) {
  union { float f; unsigned i; } c; c.f = f;
  unsigned r = c.i + 0x7fffu + ((c.i >> 16) & 1u);
  return (u16)(r >> 16);
}

// ---------------------------------------------------------------------------
// f32 -> bf16 bulk convert, 8 elems/thread, grid-stride.
// ---------------------------------------------------------------------------
__global__ __launch_bounds__(256)
void cvt_f32_bf16_k(const float* __restrict__ src, u16* __restrict__ dst, int n8)
{
  int i = blockIdx.x * blockDim.x + threadIdx.x;
  const int stride = gridDim.x * blockDim.x;
  for (; i < n8; i += stride) {
    float4 a = ((const float4*)src)[2 * i];
    float4 b = ((const float4*)src)[2 * i + 1];
    short8 o;
    o[0] = (short)f2bf(a.x); o[1] = (short)f2bf(a.y);
    o[2] = (short)f2bf(a.z); o[3] = (short)f2bf(a.w);
    o[4] = (short)f2bf(b.x); o[5] = (short)f2bf(b.y);
    o[6] = (short)f2bf(b.z); o[7] = (short)f2bf(b.w);
    ((short8*)dst)[i] = o;
  }
}

// ---------------------------------------------------------------------------
// GEMM C[M][N] = A[M][K](bf16) @ W^T, W stored [N][K] row-major (bf16).
// MODE 0: fused QKV (N=6144). MODE 1: plain (N=4096). OutT: u16(bf16)/float.
// m97 structure: 128x128 tile, BK=32, 4 waves, global_load_lds width 16.
// ---------------------------------------------------------------------------
template<int MODE, typename OutT>
__global__ __launch_bounds__(256, 2)
void gemm_bt(const u16* __restrict__ A, const u16* __restrict__ W0,
             const u16* __restrict__ W1, const u16* __restrict__ W2,
             OutT* __restrict__ C)
{
  constexpr int K = 4096;
  constexpr int LDC = (MODE == 0) ? 6144 : 4096;

  __shared__ __align__(16) u16 sA[128 * 32];
  __shared__ __align__(16) u16 sB[128 * 32];

  const int tid = threadIdx.x;
  const int wid = tid >> 6, lane = tid & 63;
  const int g = lane >> 4, li = lane & 15;
  const int bn = blockIdx.x, bm = blockIdx.y;
  const int wr = wid >> 1, wc = wid & 1;
  const int n0 = bn * 128;

  const u16* Wp; int nrow0;
  if (MODE == 0) {
    if (n0 < 4096)      { Wp = W0; nrow0 = n0; }
    else if (n0 < 5120) { Wp = W1; nrow0 = n0 - 4096; }
    else                { Wp = W2; nrow0 = n0 - 5120; }
  } else { Wp = W0; nrow0 = n0; }

  const u16* aptr = A  + (size_t)(bm * 128 + (tid >> 2)) * K + (tid & 3) * 8;
  const u16* bptr = Wp + (size_t)(nrow0   + (tid >> 2)) * K + (tid & 3) * 8;
  u16* sAw = sA + wid * 512;   // wave-uniform LDS base
  u16* sBw = sB + wid * 512;

  f32x4 acc[4][4] = {};

  for (int k0 = 0; k0 < K; k0 += 32) {
    gload_lds16(aptr + k0,           sAw);          // rows 0..63
    gload_lds16(aptr + k0 + 64 * K,  sAw + 2048);   // rows 64..127
    gload_lds16(bptr + k0,           sBw);
    gload_lds16(bptr + k0 + 64 * K,  sBw + 2048);
    __syncthreads();   // compiler drains vmcnt(0) before barrier

    short8 af[4], bfv[4];
#pragma unroll
    for (int m = 0; m < 4; ++m)
      af[m]  = *(const short8*)(sA + (wr * 64 + m * 16 + li) * 32 + g * 8);
#pragma unroll
    for (int n = 0; n < 4; ++n)
      bfv[n] = *(const short8*)(sB + (wc * 64 + n * 16 + li) * 32 + g * 8);
#pragma unroll
    for (int m = 0; m < 4; ++m)
#pragma unroll
      for (int n = 0; n < 4; ++n)
        acc[m][n] = __builtin_amdgcn_mfma_f32_16x16x32_bf16(af[m], bfv[n], acc[m][n], 0, 0, 0);
    __syncthreads();
  }

#pragma unroll
  for (int m = 0; m < 4; ++m)
#pragma unroll
    for (int n = 0; n < 4; ++n)
#pragma unroll
      for (int j = 0; j < 4; ++j) {
        int row = bm * 128 + wr * 64 + m * 16 + g * 4 + j;
        int col = n0 + wc * 64 + n * 16 + li;
        float v = acc[m][n][j];
        if constexpr (sizeof(OutT) == 2) C[(size_t)row * LDC + col] = (OutT)f2bf(v);
        else                             C[(size_t)row * LDC + col] = (OutT)v;
      }
}

// ---------------------------------------------------------------------------
// Per-head RMSNorm + RoPE. One wave per head-row; lane l holds d=l and d=l+64.
// ---------------------------------------------------------------------------
__global__ __launch_bounds__(256)
void norm_rope(const u16* __restrict__ qkv, const float* __restrict__ qw,
               const float* __restrict__ kw, u16* __restrict__ Qo,
               u16* __restrict__ Ko)
{
  const int tid = threadIdx.x;
  const int wid = tid >> 6, l = tid & 63;
  const int idx = blockIdx.x * 4 + wid;

  const u16* src; const float* w; u16* dst; int t;
  if (idx < 131072) {                       // q rows: B*T*32
    int row = idx >> 5, h = idx & 31;
    int b = row >> 11; t = row & 2047;
    src = qkv + (size_t)row * 6144 + h * 128;
    w = qw;
    dst = Qo + (((size_t)(b * 32 + h)) * 2048 + t) * 128;
  } else {                                  // k rows: B*T*8
    int j = idx - 131072;
    int row = j >> 3, hk = j & 7;
    int b = row >> 11; t = row & 2047;
    src = qkv + (size_t)row * 6144 + 4096 + hk * 128;
    w = kw;
    dst = Ko + (((size_t)(b * 8 + hk)) * 2048 + t) * 128;
  }

  float x1 = bf2f(src[l]), x2 = bf2f(src[l + 64]);
  float ss = x1 * x1 + x2 * x2;
#pragma unroll
  for (int off = 32; off; off >>= 1) ss += __shfl_xor(ss, off);
  float rn = rsqrtf(ss * (1.0f / 128.0f) + 1e-6f);
  float y1 = x1 * rn * w[l];
  float y2 = x2 * rn * w[l + 64];

  float ang = (float)t * expf((float)l * -0.21586735246819178f);
  float c = cosf(ang), s = sinf(ang);
  dst[l]      = f2bf(y1 * c - y2 * s);
  dst[l + 64] = f2bf(y2 * c + y1 * s);
}

// ---------------------------------------------------------------------------
// V transpose: qkv V-cols [B*T][5120+hkv*128+d] -> Vt [B][8][128][T]
// ---------------------------------------------------------------------------
__global__ __launch_bounds__(256)
void transpose_v(const u16* __restrict__ qkv, u16* __restrict__ Vt)
{
  const int tblk = blockIdx.x, bh = blockIdx.y;
  const int b = bh >> 3, hk = bh & 7;
  const int tid = threadIdx.x;
  __shared__ __align__(16) u16 tile[64][136];

#pragma unroll
  for (int r = 0; r < 4; ++r) {
    int u = tid + r * 256;
    int row = u >> 4, cu = u & 15;
    short8 v = *(const short8*)(qkv + (size_t)(b * 2048 + tblk * 64 + row) * 6144
                                + 5120 + hk * 128 + cu * 8);
    *(short8*)(&tile[row][cu * 8]) = v;
  }
  __syncthreads();
#pragma unroll
  for (int it = 0; it < 4; ++it) {
    int u = tid + it * 256;
    int d = u & 127, tg = u >> 7;
    short8 wv8;
#pragma unroll
    for (int j = 0; j < 8; ++j) wv8[j] = (short)tile[tg * 8 + j][d];
    *(short8*)(Vt + ((size_t)(b * 8 + hk) * 128 + d) * 2048 + tblk * 64 + tg * 8) = wv8;
  }
}

// ---------------------------------------------------------------------------
// Causal flash attention, BARRIER-FREE. Grid (T/64, B*Hq), 4 waves x 16 rows.
// K/V fragments are loaded global->VGPR directly (all 4 waves share the same
// 32KB/iter K+V working set -> L1/L2 serve it). sP is per-wave (no barrier).
// qt reversed so heavy blocks launch first.
// ---------------------------------------------------------------------------
__global__ __launch_bounds__(256, 2)
void attn_fwd(const u16* __restrict__ Q, const u16* __restrict__ Kc,
              const u16* __restrict__ Vt, u16* __restrict__ O)
{
  const int qt = (int)gridDim.x - 1 - (int)blockIdx.x;   // heavy first
  const int bh = blockIdx.y;
  const int b = bh >> 5, h = bh & 31, hkv = h >> 2;
  const int tid = threadIdx.x, wid = tid >> 6, lane = tid & 63;
  const int g = lane >> 4, li = lane & 15;

  __shared__ __align__(16) u16 sP[4][16][72];   // per-wave P, +8 pad

  const u16* Kb = Kc + ((size_t)(b * 8 + hkv)) * 2048 * 128;
  const u16* Vb = Vt + ((size_t)(b * 8 + hkv)) * 128 * 2048;

  // Q fragments, hoisted (lane: row=li, d = kk*32 + g*8 .. +7)
  const u16* qrow = Q + (((size_t)(b * 32 + h)) * 2048 + qt * 64 + wid * 16 + li) * 128;
  short8 qf[4];
#pragma unroll
  for (int kk = 0; kk < 4; ++kk) qf[kk] = *(const short8*)(qrow + kk * 32 + g * 8);

  f32x4 oacc[8] = {};
  float mrun[4], lrun[4];
#pragma unroll
  for (int r = 0; r < 4; ++r) { mrun[r] = -INFINITY; lrun[r] = 0.f; }
  const float scale = 0.08838834764831845f;   // 128^-0.5

  for (int kt = 0; kt <= qt; ++kt) {
    const int kv0 = kt * 64;

    // S = Q K^T  (16 MFMA, K frags direct from global)
    f32x4 sacc[4] = {};
    short8 kf[4][4];
#pragma unroll
    for (int n = 0; n < 4; ++n) {
      const u16* krow = Kb + (size_t)(kv0 + n * 16 + li) * 128 + g * 8;
#pragma unroll
      for (int kk = 0; kk < 4; ++kk)
        kf[n][kk] = *(const short8*)(krow + kk * 32);
    }
    __builtin_amdgcn_s_setprio(1);
#pragma unroll
    for (int n = 0; n < 4; ++n)
#pragma unroll
      for (int kk = 0; kk < 4; ++kk)
        sacc[n] = __builtin_amdgcn_mfma_f32_16x16x32_bf16(qf[kk], kf[n][kk], sacc[n], 0, 0, 0);
    __builtin_amdgcn_s_setprio(0);

    // scale + causal mask (accumulator: row = g*4+r, col = n*16+li)
    const int qrow0 = qt * 64 + wid * 16 + g * 4;
    const bool diag = (kt == qt);
    float sc[4][4];
#pragma unroll
    for (int n = 0; n < 4; ++n) {
      int col = kv0 + n * 16 + li;
#pragma unroll
      for (int r = 0; r < 4; ++r) {
        float v = sacc[n][r] * scale;
        if (diag && col > qrow0 + r) v = -INFINITY;
        sc[n][r] = v;
      }
    }

    // online softmax over 16-lane groups
    float corr[4];
#pragma unroll
    for (int r = 0; r < 4; ++r) {
      float m = fmaxf(fmaxf(sc[0][r], sc[1][r]), fmaxf(sc[2][r], sc[3][r]));
#pragma unroll
      for (int off = 1; off < 16; off <<= 1) m = fmaxf(m, __shfl_xor(m, off));
      float mn = fmaxf(mrun[r], m);
      corr[r] = __expf(mrun[r] - mn);
      mrun[r] = mn;
    }
    float psum[4] = {0.f, 0.f, 0.f, 0.f};
#pragma unroll
    for (int n = 0; n < 4; ++n)
#pragma unroll
      for (int r = 0; r < 4; ++r) {
        float p = __expf(sc[n][r] - mrun[r]);
        psum[r] += p;
        sP[wid][g * 4 + r][n * 16 + li] = f2bf(p);
      }
#pragma unroll
    for (int r = 0; r < 4; ++r) {
      float s = psum[r];
#pragma unroll
      for (int off = 1; off < 16; off <<= 1) s += __shfl_xor(s, off);
      lrun[r] = lrun[r] * corr[r] + s;
#pragma unroll
      for (int dt = 0; dt < 8; ++dt) oacc[dt][r] *= corr[r];
    }

    // O += P @ V  (16 MFMA, V frags direct from global Vt [d][t])
#pragma unroll
    for (int ks = 0; ks < 2; ++ks) {
      short8 pf = *(const short8*)(&sP[wid][li][ks * 32 + g * 8]);
      short8 vf[8];
#pragma unroll
      for (int dt = 0; dt < 8; ++dt)
        vf[dt] = *(const short8*)(Vb + (size_t)(dt * 16 + li) * 2048 + kv0 + ks * 32 + g * 8);
      __builtin_amdgcn_s_setprio(1);
#pragma unroll
      for (int dt = 0; dt < 8; ++dt)
        oacc[dt] = __builtin_amdgcn_mfma_f32_16x16x32_bf16(pf, vf[dt], oacc[dt], 0, 0, 0);
      __builtin_amdgcn_s_setprio(0);
    }
  }

  float inv[4];
#pragma unroll
  for (int r = 0; r < 4; ++r) inv[r] = 1.f / lrun[r];
  const size_t orow0 = (size_t)(b * 2048 + qt * 64 + wid * 16 + g * 4);
#pragma unroll
  for (int dt = 0; dt < 8; ++dt)
#pragma unroll
    for (int r = 0; r < 4; ++r)
      O[(orow0 + r) * 4096 + h * 128 + dt * 16 + li] = f2bf(oacc[dt][r] * inv[r]);
}

// ---------------------------------------------------------------------------
extern "C" void kernel_launch(void* const* d_in, const int* in_sizes, int n_in,
                              void* d_out, int out_size, void* d_ws, size_t ws_size,
                              hipStream_t stream) {
  const float* hs  = (const float*)d_in[0];
  const float* wq  = (const float*)d_in[1];
  const float* wk  = (const float*)d_in[2];
  const float* wv  = (const float*)d_in[3];
  const float* wo  = (const float*)d_in[4];
  const float* qnw = (const float*)d_in[5];
  const float* knw = (const float*)d_in[6];
  float* out = (float*)d_out;

  char* ws = (char*)d_ws;
  u16* qkv = (u16*)(ws);                  // [4096][6144] bf16   50.33 MB
  u16* qr  = (u16*)(ws + 50331648);       // [2][32][2048][128]  33.55 MB
  u16* kr  = (u16*)(ws + 83886080);       // [2][8][2048][128]    8.39 MB
  u16* vt  = (u16*)(ws + 92274688);       // [2][8][128][2048]    8.39 MB
  u16* hsb = (u16*)(ws + 100663296);      // hs bf16             33.55 MB
  u16* wqb = (u16*)(ws + 134217728);      // wq bf16             33.55 MB
  u16* wkb = (u16*)(ws + 167772160);      // wk bf16              8.39 MB
  u16* wvb = (u16*)(ws + 176160768);      // wv bf16              8.39 MB
  u16* ao  = (u16*)(ws);                  // attn out reuses dead qkv region
  u16* wob = qr;                          // wo bf16 reuses dead qr region

  cvt_f32_bf16_k<<<dim3(2048), dim3(256), 0, stream>>>(hs, hsb, 16777216 / 8);
  cvt_f32_bf16_k<<<dim3(2048), dim3(256), 0, stream>>>(wq, wqb, 16777216 / 8);
  cvt_f32_bf16_k<<<dim3(1024), dim3(256), 0, stream>>>(wk, wkb, 4194304 / 8);
  cvt_f32_bf16_k<<<dim3(1024), dim3(256), 0, stream>>>(wv, wvb, 4194304 / 8);

  gemm_bt<0, u16><<<dim3(48, 32), dim3(256), 0, stream>>>(hsb, wqb, wkb, wvb, qkv);
  norm_rope<<<dim3(40960), dim3(256), 0, stream>>>(qkv, qnw, knw, qr, kr);
  transpose_v<<<dim3(32, 16), dim3(256), 0, stream>>>(qkv, vt);
  attn_fwd<<<dim3(32, 64), dim3(256), 0, stream>>>(qr, kr, vt, ao);

  cvt_f32_bf16_k<<<dim3(2048), dim3(256), 0, stream>>>(wo, wob, 16777216 / 8);
  gemm_bt<1, float><<<dim3(32, 32), dim3(256), 0, stream>>>(ao, wob, nullptr, nullptr, out);
}

// Round 4
// 800.111 us; speedup vs baseline: 1.6930x; 1.6930x over previous
//
#include <hip/hip_runtime.h>
#include <math.h>

typedef unsigned short u16;
typedef __attribute__((ext_vector_type(8))) short short8;
typedef __attribute__((ext_vector_type(4))) float f32x4;

#define AS1 __attribute__((address_space(1)))
#define AS3 __attribute__((address_space(3)))

__device__ __forceinline__ void gload_lds16(const u16* g, u16* l) {
  __builtin_amdgcn_global_load_lds((AS1 void*)g, (AS3 void*)l, 16, 0, 0);
}

__device__ __forceinline__ float bf2f(u16 u) {
  union { unsigned i; float f; } c; c.i = ((unsigned)u) << 16; return c.f;
}
__device__ __forceinline__ u16 f2bf(float f) {
  union { float f; unsigned i; } c; c.f = f;
  unsigned r = c.i + 0x7fffu + ((c.i >> 16) & 1u);
  return (u16)(r >> 16);
}

// ---------------------------------------------------------------------------
// f32 -> bf16 bulk convert, 8 elems/thread, grid-stride.
// ---------------------------------------------------------------------------
__global__ __launch_bounds__(256)
void cvt_f32_bf16_k(const float* __restrict__ src, u16* __restrict__ dst, int n8)
{
  int i = blockIdx.x * blockDim.x + threadIdx.x;
  const int stride = gridDim.x * blockDim.x;
  for (; i < n8; i += stride) {
    float4 a = ((const float4*)src)[2 * i];
    float4 b = ((const float4*)src)[2 * i + 1];
    short8 o;
    o[0] = (short)f2bf(a.x); o[1] = (short)f2bf(a.y);
    o[2] = (short)f2bf(a.z); o[3] = (short)f2bf(a.w);
    o[4] = (short)f2bf(b.x); o[5] = (short)f2bf(b.y);
    o[6] = (short)f2bf(b.z); o[7] = (short)f2bf(b.w);
    ((short8*)dst)[i] = o;
  }
}

// ---------------------------------------------------------------------------
// GEMM C[M][N] = A[M][K](bf16) @ W^T, W stored [N][K] row-major (bf16).
// MODE 0: fused QKV (N=6144). MODE 1: plain (N=4096). OutT: u16(bf16)/float.
// m97 structure: 128x128 tile, BK=32, 4 waves, global_load_lds width 16.
// ---------------------------------------------------------------------------
template<int MODE, typename OutT>
__global__ __launch_bounds__(256, 2)
void gemm_bt(const u16* __restrict__ A, const u16* __restrict__ W0,
             const u16* __restrict__ W1, const u16* __restrict__ W2,
             OutT* __restrict__ C)
{
  constexpr int K = 4096;
  constexpr int LDC = (MODE == 0) ? 6144 : 4096;

  __shared__ __align__(16) u16 sA[128 * 32];
  __shared__ __align__(16) u16 sB[128 * 32];

  const int tid = threadIdx.x;
  const int wid = tid >> 6, lane = tid & 63;
  const int g = lane >> 4, li = lane & 15;
  const int bn = blockIdx.x, bm = blockIdx.y;
  const int wr = wid >> 1, wc = wid & 1;
  const int n0 = bn * 128;

  const u16* Wp; int nrow0;
  if (MODE == 0) {
    if (n0 < 4096)      { Wp = W0; nrow0 = n0; }
    else if (n0 < 5120) { Wp = W1; nrow0 = n0 - 4096; }
    else                { Wp = W2; nrow0 = n0 - 5120; }
  } else { Wp = W0; nrow0 = n0; }

  const u16* aptr = A  + (size_t)(bm * 128 + (tid >> 2)) * K + (tid & 3) * 8;
  const u16* bptr = Wp + (size_t)(nrow0   + (tid >> 2)) * K + (tid & 3) * 8;
  u16* sAw = sA + wid * 512;   // wave-uniform LDS base
  u16* sBw = sB + wid * 512;

  f32x4 acc[4][4] = {};

  for (int k0 = 0; k0 < K; k0 += 32) {
    gload_lds16(aptr + k0,           sAw);          // rows 0..63
    gload_lds16(aptr + k0 + 64 * K,  sAw + 2048);   // rows 64..127
    gload_lds16(bptr + k0,           sBw);
    gload_lds16(bptr + k0 + 64 * K,  sBw + 2048);
    __syncthreads();   // compiler drains vmcnt(0) before barrier

    short8 af[4], bfv[4];
#pragma unroll
    for (int m = 0; m < 4; ++m)
      af[m]  = *(const short8*)(sA + (wr * 64 + m * 16 + li) * 32 + g * 8);
#pragma unroll
    for (int n = 0; n < 4; ++n)
      bfv[n] = *(const short8*)(sB + (wc * 64 + n * 16 + li) * 32 + g * 8);
#pragma unroll
    for (int m = 0; m < 4; ++m)
#pragma unroll
      for (int n = 0; n < 4; ++n)
        acc[m][n] = __builtin_amdgcn_mfma_f32_16x16x32_bf16(af[m], bfv[n], acc[m][n], 0, 0, 0);
    __syncthreads();
  }

#pragma unroll
  for (int m = 0; m < 4; ++m)
#pragma unroll
    for (int n = 0; n < 4; ++n)
#pragma unroll
      for (int j = 0; j < 4; ++j) {
        int row = bm * 128 + wr * 64 + m * 16 + g * 4 + j;
        int col = n0 + wc * 64 + n * 16 + li;
        float v = acc[m][n][j];
        if constexpr (sizeof(OutT) == 2) C[(size_t)row * LDC + col] = (OutT)f2bf(v);
        else                             C[(size_t)row * LDC + col] = (OutT)v;
      }
}

// ---------------------------------------------------------------------------
// Per-head RMSNorm + RoPE. One wave per head-row; lane l holds d=l and d=l+64.
// ---------------------------------------------------------------------------
__global__ __launch_bounds__(256)
void norm_rope(const u16* __restrict__ qkv, const float* __restrict__ qw,
               const float* __restrict__ kw, u16* __restrict__ Qo,
               u16* __restrict__ Ko)
{
  const int tid = threadIdx.x;
  const int wid = tid >> 6, l = tid & 63;
  const int idx = blockIdx.x * 4 + wid;

  const u16* src; const float* w; u16* dst; int t;
  if (idx < 131072) {                       // q rows: B*T*32
    int row = idx >> 5, h = idx & 31;
    int b = row >> 11; t = row & 2047;
    src = qkv + (size_t)row * 6144 + h * 128;
    w = qw;
    dst = Qo + (((size_t)(b * 32 + h)) * 2048 + t) * 128;
  } else {                                  // k rows: B*T*8
    int j = idx - 131072;
    int row = j >> 3, hk = j & 7;
    int b = row >> 11; t = row & 2047;
    src = qkv + (size_t)row * 6144 + 4096 + hk * 128;
    w = kw;
    dst = Ko + (((size_t)(b * 8 + hk)) * 2048 + t) * 128;
  }

  float x1 = bf2f(src[l]), x2 = bf2f(src[l + 64]);
  float ss = x1 * x1 + x2 * x2;
#pragma unroll
  for (int off = 32; off; off >>= 1) ss += __shfl_xor(ss, off);
  float rn = rsqrtf(ss * (1.0f / 128.0f) + 1e-6f);
  float y1 = x1 * rn * w[l];
  float y2 = x2 * rn * w[l + 64];

  float ang = (float)t * expf((float)l * -0.21586735246819178f);
  float c = cosf(ang), s = sinf(ang);
  dst[l]      = f2bf(y1 * c - y2 * s);
  dst[l + 64] = f2bf(y2 * c + y1 * s);
}

// ---------------------------------------------------------------------------
// V transpose: qkv V-cols [B*T][5120+hkv*128+d] -> Vt [B][8][128][T]
// ---------------------------------------------------------------------------
__global__ __launch_bounds__(256)
void transpose_v(const u16* __restrict__ qkv, u16* __restrict__ Vt)
{
  const int tblk = blockIdx.x, bh = blockIdx.y;
  const int b = bh >> 3, hk = bh & 7;
  const int tid = threadIdx.x;
  __shared__ __align__(16) u16 tile[64][136];

#pragma unroll
  for (int r = 0; r < 4; ++r) {
    int u = tid + r * 256;
    int row = u >> 4, cu = u & 15;
    short8 v = *(const short8*)(qkv + (size_t)(b * 2048 + tblk * 64 + row) * 6144
                                + 5120 + hk * 128 + cu * 8);
    *(short8*)(&tile[row][cu * 8]) = v;
  }
  __syncthreads();
#pragma unroll
  for (int it = 0; it < 4; ++it) {
    int u = tid + it * 256;
    int d = u & 127, tg = u >> 7;
    short8 wv8;
#pragma unroll
    for (int j = 0; j < 8; ++j) wv8[j] = (short)tile[tg * 8 + j][d];
    *(short8*)(Vt + ((size_t)(b * 8 + hk) * 128 + d) * 2048 + tblk * 64 + tg * 8) = wv8;
  }
}

// ---------------------------------------------------------------------------
// Causal flash attention, T3 double-buffered pipeline.
// Grid (16, B*Hq), 512 thr = 8 waves x 16 q-rows (QBLK=128), KVBLK=64.
// K/V tiles double-buffered in LDS; next tile's global_load_lds issued at
// iteration START; single raw s_barrier + vmcnt(0) at iteration END (drain
// hidden under ~1400cy of MFMA+softmax). XOR swizzle pre-applied on global
// src (linear LDS dest), de-swizzled on ds_read (both-sides, rule #21).
// ---------------------------------------------------------------------------
__global__ __launch_bounds__(512, 2)
void attn_fwd(const u16* __restrict__ Q, const u16* __restrict__ Kc,
              const u16* __restrict__ Vt, u16* __restrict__ O)
{
  const int qt = 15 - (int)blockIdx.x;   // heavy blocks first
  const int bh = blockIdx.y;
  const int b = bh >> 5, h = bh & 31, hkv = h >> 2;
  const int tid = threadIdx.x, wid = tid >> 6, lane = tid & 63;
  const int g = lane >> 4, li = lane & 15;

  __shared__ __align__(16) u16 sK[2][64 * 128];   // 2 x 16 KB
  __shared__ __align__(16) u16 sV[2][128 * 64];   // 2 x 16 KB
  __shared__ __align__(16) u16 sP[8][16][72];     // per-wave P, +8 pad

  const u16* Kb = Kc + ((size_t)(b * 8 + hkv)) * 2048 * 128;
  const u16* Vb = Vt + ((size_t)(b * 8 + hkv)) * 128 * 2048;

  // staging coords: 512 threads x 2 units each per 16KB tile
  const int krow = tid >> 4, kc16 = tid & 15;          // K rows 0..31 (+32)
  const int vrow = tid >> 3, vc8 = tid & 7;            // V rows 0..63 (+64)
  const u16* kS0 = Kb + (size_t)krow * 128 + ((kc16 ^ (krow & 7)) * 8);
  const u16* kS1 = Kb + (size_t)(krow + 32) * 128 + ((kc16 ^ (krow & 7)) * 8);
  const u16* vS0 = Vb + (size_t)vrow * 2048 + ((vc8 ^ (vrow & 7)) * 8);
  const u16* vS1 = Vb + (size_t)(vrow + 64) * 2048 + ((vc8 ^ ((vrow + 64) & 7)) * 8);
  u16* const kD0 = (u16*)sK[0] + wid * 512;            // + cur*8192
  u16* const vD0 = (u16*)sV[0] + wid * 512;

  // Q fragments hoisted (lane: row=li, d = kk*32 + g*8 .. +7)
  const u16* qrow = Q + (((size_t)(b * 32 + h)) * 2048 + qt * 128 + wid * 16 + li) * 128;
  short8 qf[4];
#pragma unroll
  for (int kk = 0; kk < 4; ++kk) qf[kk] = *(const short8*)(qrow + kk * 32 + g * 8);

  f32x4 oacc[8] = {};
  float mrun[4], lrun[4];
#pragma unroll
  for (int r = 0; r < 4; ++r) { mrun[r] = -INFINITY; lrun[r] = 0.f; }
  const float scale = 0.08838834764831845f;   // 128^-0.5

  const int nt = 2 * qt + 2;

  // prologue: stage tile 0 into buffer 0
  gload_lds16(kS0, kD0);          gload_lds16(kS1, kD0 + 4096);
  gload_lds16(vS0, vD0);          gload_lds16(vS1, vD0 + 4096);
  asm volatile("s_waitcnt vmcnt(0)" ::: "memory");
  __builtin_amdgcn_s_barrier();

  int cur = 0;
  for (int kt = 0; kt < nt; ++kt) {
    const int kv0 = kt * 64;
    // issue next tile's staging immediately (hidden under this tile's compute)
    if (kt + 1 < nt) {
      const int nx = kv0 + 64;
      u16* kD = kD0 + (cur ^ 1) * 8192;
      u16* vD = vD0 + (cur ^ 1) * 8192;
      gload_lds16(kS0 + (size_t)nx * 128, kD);
      gload_lds16(kS1 + (size_t)nx * 128, kD + 4096);
      gload_lds16(vS0 + nx, vD);
      gload_lds16(vS1 + nx, vD + 4096);
    }

    const u16* sKc = sK[cur];
    const u16* sVc = sV[cur];

    // S = Q K^T   (16 MFMA/wave)
    f32x4 sacc[4] = {};
#pragma unroll
    for (int n = 0; n < 4; ++n) {
      int kr = n * 16 + li;
#pragma unroll
      for (int kk = 0; kk < 4; ++kk) {
        int c16 = (kk * 4 + g) ^ (kr & 7);
        short8 kf = *(const short8*)(sKc + kr * 128 + c16 * 8);
        sacc[n] = __builtin_amdgcn_mfma_f32_16x16x32_bf16(qf[kk], kf, sacc[n], 0, 0, 0);
      }
    }

    // scale + causal mask (acc: row = g*4+r, col = n*16+li); mask always
    const int qrow0 = qt * 128 + wid * 16 + g * 4;
    float sc[4][4];
#pragma unroll
    for (int n = 0; n < 4; ++n) {
      int col = kv0 + n * 16 + li;
#pragma unroll
      for (int r = 0; r < 4; ++r) {
        float v = sacc[n][r] * scale;
        if (col > qrow0 + r) v = -INFINITY;
        sc[n][r] = v;
      }
    }

    // online softmax over 16-lane groups
    float corr[4];
#pragma unroll
    for (int r = 0; r < 4; ++r) {
      float m = fmaxf(fmaxf(sc[0][r], sc[1][r]), fmaxf(sc[2][r], sc[3][r]));
#pragma unroll
      for (int off = 1; off < 16; off <<= 1) m = fmaxf(m, __shfl_xor(m, off));
      float mn = fmaxf(mrun[r], m);
      corr[r] = __expf(mrun[r] - mn);
      mrun[r] = mn;
    }
    float psum[4] = {0.f, 0.f, 0.f, 0.f};
#pragma unroll
    for (int n = 0; n < 4; ++n)
#pragma unroll
      for (int r = 0; r < 4; ++r) {
        float p = __expf(sc[n][r] - mrun[r]);
        psum[r] += p;
        sP[wid][g * 4 + r][n * 16 + li] = f2bf(p);
      }
#pragma unroll
    for (int r = 0; r < 4; ++r) {
      float s = psum[r];
#pragma unroll
      for (int off = 1; off < 16; off <<= 1) s += __shfl_xor(s, off);
      lrun[r] = lrun[r] * corr[r] + s;
#pragma unroll
      for (int dt = 0; dt < 8; ++dt) oacc[dt][r] *= corr[r];
    }

    // O += P @ V   (16 MFMA/wave)
#pragma unroll
    for (int ks = 0; ks < 2; ++ks) {
      short8 pf = *(const short8*)(&sP[wid][li][ks * 32 + g * 8]);
      __builtin_amdgcn_s_setprio(1);
#pragma unroll
      for (int dt = 0; dt < 8; ++dt) {
        int vr = dt * 16 + li;
        int c16 = (ks * 4 + g) ^ (vr & 7);
        short8 vf = *(const short8*)(sVc + vr * 64 + c16 * 8);
        oacc[dt] = __builtin_amdgcn_mfma_f32_16x16x32_bf16(pf, vf, oacc[dt], 0, 0, 0);
      }
      __builtin_amdgcn_s_setprio(0);
    }

    // single end-of-iteration sync: prefetch drain (hidden) + barrier
    asm volatile("s_waitcnt lgkmcnt(0)" ::: "memory");
    asm volatile("s_waitcnt vmcnt(0)" ::: "memory");
    __builtin_amdgcn_s_barrier();
    cur ^= 1;
  }

  float inv[4];
#pragma unroll
  for (int r = 0; r < 4; ++r) inv[r] = 1.f / lrun[r];
  const size_t orow0 = (size_t)(b * 2048 + qt * 128 + wid * 16 + g * 4);
#pragma unroll
  for (int dt = 0; dt < 8; ++dt)
#pragma unroll
    for (int r = 0; r < 4; ++r)
      O[(orow0 + r) * 4096 + h * 128 + dt * 16 + li] = f2bf(oacc[dt][r] * inv[r]);
}

// ---------------------------------------------------------------------------
extern "C" void kernel_launch(void* const* d_in, const int* in_sizes, int n_in,
                              void* d_out, int out_size, void* d_ws, size_t ws_size,
                              hipStream_t stream) {
  const float* hs  = (const float*)d_in[0];
  const float* wq  = (const float*)d_in[1];
  const float* wk  = (const float*)d_in[2];
  const float* wv  = (const float*)d_in[3];
  const float* wo  = (const float*)d_in[4];
  const float* qnw = (const float*)d_in[5];
  const float* knw = (const float*)d_in[6];
  float* out = (float*)d_out;

  char* ws = (char*)d_ws;
  u16* qkv = (u16*)(ws);                  // [4096][6144] bf16   50.33 MB
  u16* qr  = (u16*)(ws + 50331648);       // [2][32][2048][128]  33.55 MB
  u16* kr  = (u16*)(ws + 83886080);       // [2][8][2048][128]    8.39 MB
  u16* vt  = (u16*)(ws + 92274688);       // [2][8][128][2048]    8.39 MB
  u16* hsb = (u16*)(ws + 100663296);      // hs bf16             33.55 MB
  u16* wqb = (u16*)(ws + 134217728);      // wq bf16             33.55 MB
  u16* wkb = (u16*)(ws + 167772160);      // wk bf16              8.39 MB
  u16* wvb = (u16*)(ws + 176160768);      // wv bf16              8.39 MB
  u16* ao  = (u16*)(ws);                  // attn out reuses dead qkv region
  u16* wob = qr;                          // wo bf16 reuses dead qr region

  cvt_f32_bf16_k<<<dim3(2048), dim3(256), 0, stream>>>(hs, hsb, 16777216 / 8);
  cvt_f32_bf16_k<<<dim3(2048), dim3(256), 0, stream>>>(wq, wqb, 16777216 / 8);
  cvt_f32_bf16_k<<<dim3(1024), dim3(256), 0, stream>>>(wk, wkb, 4194304 / 8);
  cvt_f32_bf16_k<<<dim3(1024), dim3(256), 0, stream>>>(wv, wvb, 4194304 / 8);

  gemm_bt<0, u16><<<dim3(48, 32), dim3(256), 0, stream>>>(hsb, wqb, wkb, wvb, qkv);
  norm_rope<<<dim3(40960), dim3(256), 0, stream>>>(qkv, qnw, knw, qr, kr);
  transpose_v<<<dim3(32, 16), dim3(256), 0, stream>>>(qkv, vt);
  attn_fwd<<<dim3(16, 64), dim3(512), 0, stream>>>(qr, kr, vt, ao);

  cvt_f32_bf16_k<<<dim3(2048), dim3(256), 0, stream>>>(wo, wob, 16777216 / 8);
  gemm_bt<1, float><<<dim3(32, 32), dim3(256), 0, stream>>>(ao, wob, nullptr, nullptr, out);
}

// Round 5
// 641.486 us; speedup vs baseline: 2.1116x; 1.2473x over previous
//
#include <hip/hip_runtime.h>
#include <math.h>

typedef unsigned short u16;
typedef __attribute__((ext_vector_type(8))) short short8;
typedef __attribute__((ext_vector_type(4))) float f32x4;
typedef __attribute__((ext_vector_type(16))) float f32x16;

#define AS1 __attribute__((address_space(1)))
#define AS3 __attribute__((address_space(3)))

__device__ __forceinline__ void gload_lds16(const u16* g, u16* l) {
  __builtin_amdgcn_global_load_lds((AS1 void*)g, (AS3 void*)l, 16, 0, 0);
}

__device__ __forceinline__ float bf2f(u16 u) {
  union { unsigned i; float f; } c; c.i = ((unsigned)u) << 16; return c.f;
}
__device__ __forceinline__ u16 f2bf(float f) {
  union { float f; unsigned i; } c; c.f = f;
  unsigned r = c.i + 0x7fffu + ((c.i >> 16) & 1u);
  return (u16)(r >> 16);
}

// ---------------------------------------------------------------------------
// f32 -> bf16 bulk convert, 8 elems/thread, grid-stride.
// ---------------------------------------------------------------------------
__global__ __launch_bounds__(256)
void cvt_f32_bf16_k(const float* __restrict__ src, u16* __restrict__ dst, int n8)
{
  int i = blockIdx.x * blockDim.x + threadIdx.x;
  const int stride = gridDim.x * blockDim.x;
  for (; i < n8; i += stride) {
    float4 a = ((const float4*)src)[2 * i];
    float4 b = ((const float4*)src)[2 * i + 1];
    short8 o;
    o[0] = (short)f2bf(a.x); o[1] = (short)f2bf(a.y);
    o[2] = (short)f2bf(a.z); o[3] = (short)f2bf(a.w);
    o[4] = (short)f2bf(b.x); o[5] = (short)f2bf(b.y);
    o[6] = (short)f2bf(b.z); o[7] = (short)f2bf(b.w);
    ((short8*)dst)[i] = o;
  }
}

// ---------------------------------------------------------------------------
// GEMM C[M][N] = A[M][K](bf16) @ W^T, W stored [N][K] row-major (bf16).
// MODE 0: fused QKV (N=6144). MODE 1: plain (N=4096). OutT: u16(bf16)/float.
// m97 structure: 128x128 tile, BK=32, 4 waves, global_load_lds width 16.
// ---------------------------------------------------------------------------
template<int MODE, typename OutT>
__global__ __launch_bounds__(256, 2)
void gemm_bt(const u16* __restrict__ A, const u16* __restrict__ W0,
             const u16* __restrict__ W1, const u16* __restrict__ W2,
             OutT* __restrict__ C)
{
  constexpr int K = 4096;
  constexpr int LDC = (MODE == 0) ? 6144 : 4096;

  __shared__ __align__(16) u16 sA[128 * 32];
  __shared__ __align__(16) u16 sB[128 * 32];

  const int tid = threadIdx.x;
  const int wid = tid >> 6, lane = tid & 63;
  const int g = lane >> 4, li = lane & 15;
  const int bn = blockIdx.x, bm = blockIdx.y;
  const int wr = wid >> 1, wc = wid & 1;
  const int n0 = bn * 128;

  const u16* Wp; int nrow0;
  if (MODE == 0) {
    if (n0 < 4096)      { Wp = W0; nrow0 = n0; }
    else if (n0 < 5120) { Wp = W1; nrow0 = n0 - 4096; }
    else                { Wp = W2; nrow0 = n0 - 5120; }
  } else { Wp = W0; nrow0 = n0; }

  const u16* aptr = A  + (size_t)(bm * 128 + (tid >> 2)) * K + (tid & 3) * 8;
  const u16* bptr = Wp + (size_t)(nrow0   + (tid >> 2)) * K + (tid & 3) * 8;
  u16* sAw = sA + wid * 512;   // wave-uniform LDS base
  u16* sBw = sB + wid * 512;

  f32x4 acc[4][4] = {};

  for (int k0 = 0; k0 < K; k0 += 32) {
    gload_lds16(aptr + k0,           sAw);          // rows 0..63
    gload_lds16(aptr + k0 + 64 * K,  sAw + 2048);   // rows 64..127
    gload_lds16(bptr + k0,           sBw);
    gload_lds16(bptr + k0 + 64 * K,  sBw + 2048);
    __syncthreads();   // compiler drains vmcnt(0) before barrier

    short8 af[4], bfv[4];
#pragma unroll
    for (int m = 0; m < 4; ++m)
      af[m]  = *(const short8*)(sA + (wr * 64 + m * 16 + li) * 32 + g * 8);
#pragma unroll
    for (int n = 0; n < 4; ++n)
      bfv[n] = *(const short8*)(sB + (wc * 64 + n * 16 + li) * 32 + g * 8);
#pragma unroll
    for (int m = 0; m < 4; ++m)
#pragma unroll
      for (int n = 0; n < 4; ++n)
        acc[m][n] = __builtin_amdgcn_mfma_f32_16x16x32_bf16(af[m], bfv[n], acc[m][n], 0, 0, 0);
    __syncthreads();
  }

#pragma unroll
  for (int m = 0; m < 4; ++m)
#pragma unroll
    for (int n = 0; n < 4; ++n)
#pragma unroll
      for (int j = 0; j < 4; ++j) {
        int row = bm * 128 + wr * 64 + m * 16 + g * 4 + j;
        int col = n0 + wc * 64 + n * 16 + li;
        float v = acc[m][n][j];
        if constexpr (sizeof(OutT) == 2) C[(size_t)row * LDC + col] = (OutT)f2bf(v);
        else                             C[(size_t)row * LDC + col] = (OutT)v;
      }
}

// ---------------------------------------------------------------------------
// Per-head RMSNorm + RoPE. One wave per head-row; lane l holds d=l and d=l+64.
// ---------------------------------------------------------------------------
__global__ __launch_bounds__(256)
void norm_rope(const u16* __restrict__ qkv, const float* __restrict__ qw,
               const float* __restrict__ kw, u16* __restrict__ Qo,
               u16* __restrict__ Ko)
{
  const int tid = threadIdx.x;
  const int wid = tid >> 6, l = tid & 63;
  const int idx = blockIdx.x * 4 + wid;

  const u16* src; const float* w; u16* dst; int t;
  if (idx < 131072) {                       // q rows: B*T*32
    int row = idx >> 5, h = idx & 31;
    int b = row >> 11; t = row & 2047;
    src = qkv + (size_t)row * 6144 + h * 128;
    w = qw;
    dst = Qo + (((size_t)(b * 32 + h)) * 2048 + t) * 128;
  } else {                                  // k rows: B*T*8
    int j = idx - 131072;
    int row = j >> 3, hk = j & 7;
    int b = row >> 11; t = row & 2047;
    src = qkv + (size_t)row * 6144 + 4096 + hk * 128;
    w = kw;
    dst = Ko + (((size_t)(b * 8 + hk)) * 2048 + t) * 128;
  }

  float x1 = bf2f(src[l]), x2 = bf2f(src[l + 64]);
  float ss = x1 * x1 + x2 * x2;
#pragma unroll
  for (int off = 32; off; off >>= 1) ss += __shfl_xor(ss, off);
  float rn = rsqrtf(ss * (1.0f / 128.0f) + 1e-6f);
  float y1 = x1 * rn * w[l];
  float y2 = x2 * rn * w[l + 64];

  float ang = (float)t * expf((float)l * -0.21586735246819178f);
  float c = cosf(ang), s = sinf(ang);
  dst[l]      = f2bf(y1 * c - y2 * s);
  dst[l + 64] = f2bf(y2 * c + y1 * s);
}

// ---------------------------------------------------------------------------
// V transpose: qkv V-cols [B*T][5120+hkv*128+d] -> Vt [B][8][128][T]
// ---------------------------------------------------------------------------
__global__ __launch_bounds__(256)
void transpose_v(const u16* __restrict__ qkv, u16* __restrict__ Vt)
{
  const int tblk = blockIdx.x, bh = blockIdx.y;
  const int b = bh >> 3, hk = bh & 7;
  const int tid = threadIdx.x;
  __shared__ __align__(16) u16 tile[64][136];

#pragma unroll
  for (int r = 0; r < 4; ++r) {
    int u = tid + r * 256;
    int row = u >> 4, cu = u & 15;
    short8 v = *(const short8*)(qkv + (size_t)(b * 2048 + tblk * 64 + row) * 6144
                                + 5120 + hk * 128 + cu * 8);
    *(short8*)(&tile[row][cu * 8]) = v;
  }
  __syncthreads();
#pragma unroll
  for (int it = 0; it < 4; ++it) {
    int u = tid + it * 256;
    int d = u & 127, tg = u >> 7;
    short8 wv8;
#pragma unroll
    for (int j = 0; j < 8; ++j) wv8[j] = (short)tile[tg * 8 + j][d];
    *(short8*)(Vt + ((size_t)(b * 8 + hk) * 128 + d) * 2048 + tblk * 64 + tg * 8) = wv8;
  }
}

// ---------------------------------------------------------------------------
// Causal flash attention — m214-style 32x32 structure.
// Grid (16, B*Hq), 256 thr = 4 waves x 32 q-rows (QBLK=128), KVBLK=64.
// Swapped QK^T: P = mfma(K, Q) -> lane q = lane&31 holds its full P row
// (kv_local = (r&3)+8*(r>>2)+4*hi). In-register softmax (in-lane chain +
// one shfl_xor(32)); defer-max THR=8; P->A-frag via v_cvt_pk_bf16_f32 +
// v_permlane32_swap_b32; PV B-operand straight from V^T LDS tile.
// K/V double-buffered, prefetch at top, single drain+barrier at bottom.
// LDS 64KB -> 2 blocks/CU.
// ---------------------------------------------------------------------------
__global__ __launch_bounds__(256, 2)
void attn_fwd(const u16* __restrict__ Q, const u16* __restrict__ Kc,
              const u16* __restrict__ Vt, u16* __restrict__ O)
{
  const int qt = 15 - (int)blockIdx.x;   // heavy blocks first
  const int bh = blockIdx.y;
  const int b = bh >> 5, h = bh & 31, hkv = h >> 2;
  const int tid = threadIdx.x, wid = tid >> 6;
  const int lane = tid & 63, ql = lane & 31, hi = lane >> 5;

  __shared__ __align__(16) u16 sK[2][64 * 128];   // 2 x 16 KB
  __shared__ __align__(16) u16 sV[2][128 * 64];   // 2 x 16 KB

  const u16* Kb = Kc + ((size_t)(b * 8 + hkv)) * 2048 * 128;
  const u16* Vb = Vt + ((size_t)(b * 8 + hkv)) * 128 * 2048;

  // staging sources (both-sides swizzle: pre-swizzled global, linear LDS)
  const int kr0 = tid >> 4;                                   // 0..15
  const u16* kSrc = Kb + (size_t)kr0 * 128 + (((tid & 15) ^ (kr0 & 7)) * 8);
  const int vr0 = tid >> 3;                                   // 0..31
  const u16* vSrc = Vb + (size_t)vr0 * 2048 + (((tid & 7) ^ (vr0 & 7)) * 8);
  u16* const kDst = (u16*)sK[0] + wid * 512;                  // +buf*8192 +p*2048
  u16* const vDst = (u16*)sV[0] + wid * 512;

  // Q fragments (B-operand: col=q=ql, k(d) = m*16 + hi*8 + j)
  const int qg = qt * 128 + wid * 32 + ql;
  const u16* qrow = Q + ((size_t)(b * 32 + h) * 2048 + qg) * 128;
  short8 qf[8];
#pragma unroll
  for (int m = 0; m < 8; ++m) qf[m] = *(const short8*)(qrow + m * 16 + hi * 8);

  f32x16 oacc[4] = {};
  float mrun = -INFINITY, lrun = 0.f;
  const float scale = 0.08838834764831845f;   // 128^-0.5
  const int nt = 2 * qt + 2;

  // prologue: stage tile 0 into buffer 0
#pragma unroll
  for (int p = 0; p < 4; ++p) {
    gload_lds16(kSrc + p * 2048,  kDst + p * 2048);
    gload_lds16(vSrc + p * 65536, vDst + p * 2048);
  }
  asm volatile("s_waitcnt vmcnt(0)" ::: "memory");
  __builtin_amdgcn_s_barrier();

  int cur = 0;
  for (int kt = 0; kt < nt; ++kt) {
    const int kv0 = kt * 64;
    if (kt + 1 < nt) {                       // prefetch next tile
      const u16* ks = kSrc + (size_t)(kv0 + 64) * 128;
      const u16* vs = vSrc + (kv0 + 64);
      u16* kd = kDst + (cur ^ 1) * 8192;
      u16* vd = vDst + (cur ^ 1) * 8192;
#pragma unroll
      for (int p = 0; p < 4; ++p) {
        gload_lds16(ks + p * 2048,  kd + p * 2048);
        gload_lds16(vs + p * 65536, vd + p * 2048);
      }
    }
    const u16* sKc = sK[cur];
    const u16* sVc = sV[cur];

    // swapped QK^T: P_n[kv_local][q] = K_n · Q   (16 MFMA)
    f32x16 P0 = {}, P1 = {};
    __builtin_amdgcn_s_setprio(1);
#pragma unroll
    for (int m = 0; m < 8; ++m) {
      const int c0 = ((m * 2 + hi) ^ (ql & 7)) * 8;
      short8 k0 = *(const short8*)(sKc + ql * 128 + c0);
      short8 k1 = *(const short8*)(sKc + (32 + ql) * 128 + c0);
      P0 = __builtin_amdgcn_mfma_f32_32x32x16_bf16(k0, qf[m], P0, 0, 0, 0);
      P1 = __builtin_amdgcn_mfma_f32_32x32x16_bf16(k1, qf[m], P1, 0, 0, 0);
    }
    __builtin_amdgcn_s_setprio(0);

    // scale + causal mask (lane's q = qg; kv = kv0 + n*32 + (r&3)+8*(r>>2)+4*hi)
#pragma unroll
    for (int r = 0; r < 16; ++r) {
      const int kvl = (r & 3) + 8 * (r >> 2) + 4 * hi;
      float v0 = P0[r] * scale; if (kv0 + kvl > qg)      v0 = -INFINITY; P0[r] = v0;
      float v1 = P1[r] * scale; if (kv0 + 32 + kvl > qg) v1 = -INFINITY; P1[r] = v1;
    }

    // row max (in-lane + one cross-half exchange)
    float pmax = -INFINITY;
#pragma unroll
    for (int r = 0; r < 16; ++r) pmax = fmaxf(pmax, fmaxf(P0[r], P1[r]));
    pmax = fmaxf(pmax, __shfl_xor(pmax, 32));

    if (!__all(pmax - mrun <= 8.f)) {        // defer-max (T13)
      float mnew = fmaxf(mrun, pmax);
      float corr = __expf(mrun - mnew);
      lrun *= corr;
      mrun = mnew;
#pragma unroll
      for (int r = 0; r < 16; ++r) {
        int qidx = (r & 3) + 8 * (r >> 2) + 4 * hi;
        float cr = __shfl(corr, qidx);
#pragma unroll
        for (int dt = 0; dt < 4; ++dt) oacc[dt][r] *= cr;
      }
    }

    float psum = 0.f;
#pragma unroll
    for (int r = 0; r < 16; ++r) {
      float e0 = __expf(P0[r] - mrun); P0[r] = e0; psum += e0;
      float e1 = __expf(P1[r] - mrun); P1[r] = e1; psum += e1;
    }
    psum += __shfl_xor(psum, 32);
    lrun += psum;

    // P -> A-frags (16 cvt_pk + 8 permlane32_swap) and PV (16 MFMA)
    __builtin_amdgcn_s_setprio(1);
#pragma unroll
    for (int s = 0; s < 4; ++s) {
      const int R0 = 8 * (s & 1), R1 = R0 + 4;
      float a0 = (s < 2) ? P0[R0 + 0] : P1[R0 + 0];
      float a1 = (s < 2) ? P0[R0 + 1] : P1[R0 + 1];
      float a2 = (s < 2) ? P0[R0 + 2] : P1[R0 + 2];
      float a3 = (s < 2) ? P0[R0 + 3] : P1[R0 + 3];
      float b0 = (s < 2) ? P0[R1 + 0] : P1[R1 + 0];
      float b1 = (s < 2) ? P0[R1 + 1] : P1[R1 + 1];
      float b2 = (s < 2) ? P0[R1 + 2] : P1[R1 + 2];
      float b3 = (s < 2) ? P0[R1 + 3] : P1[R1 + 3];
      unsigned y0, y1, z0, z1;
      asm("v_cvt_pk_bf16_f32 %0, %1, %2" : "=v"(y0) : "v"(a0), "v"(a1));
      asm("v_cvt_pk_bf16_f32 %0, %1, %2" : "=v"(z0) : "v"(b0), "v"(b1));
      asm("v_cvt_pk_bf16_f32 %0, %1, %2" : "=v"(y1) : "v"(a2), "v"(a3));
      asm("v_cvt_pk_bf16_f32 %0, %1, %2" : "=v"(z1) : "v"(b2), "v"(b3));
      asm("v_permlane32_swap_b32 %0, %1" : "+v"(y0), "+v"(z0));  // y0=w0 z0=w2
      asm("v_permlane32_swap_b32 %0, %1" : "+v"(y1), "+v"(z1));  // y1=w1 z1=w3
      union { unsigned u[4]; short8 v; } pa;
      pa.u[0] = y0; pa.u[1] = y1; pa.u[2] = z0; pa.u[3] = z1;
#pragma unroll
      for (int dt = 0; dt < 4; ++dt) {
        const int c = ((s * 2 + hi) ^ (ql & 7)) * 8;
        short8 vf = *(const short8*)(sVc + (dt * 32 + ql) * 64 + c);
        oacc[dt] = __builtin_amdgcn_mfma_f32_32x32x16_bf16(pa.v, vf, oacc[dt], 0, 0, 0);
      }
    }
    __builtin_amdgcn_s_setprio(0);

    asm volatile("s_waitcnt lgkmcnt(0)" ::: "memory");
    asm volatile("s_waitcnt vmcnt(0)" ::: "memory");
    __builtin_amdgcn_s_barrier();
    cur ^= 1;
  }

  // epilogue: O row q = (r&3)+8*(r>>2)+4*hi, col d = h*128 + dt*32 + ql
  float inv = 1.f / lrun;
  const int qbase = b * 2048 + qt * 128 + wid * 32;
#pragma unroll
  for (int r = 0; r < 16; ++r) {
    const int qidx = (r & 3) + 8 * (r >> 2) + 4 * hi;
    float ir = __shfl(inv, qidx);
    size_t base = (size_t)(qbase + qidx) * 4096 + h * 128 + ql;
#pragma unroll
    for (int dt = 0; dt < 4; ++dt)
      O[base + dt * 32] = f2bf(oacc[dt][r] * ir);
  }
}

// ---------------------------------------------------------------------------
extern "C" void kernel_launch(void* const* d_in, const int* in_sizes, int n_in,
                              void* d_out, int out_size, void* d_ws, size_t ws_size,
                              hipStream_t stream) {
  const float* hs  = (const float*)d_in[0];
  const float* wq  = (const float*)d_in[1];
  const float* wk  = (const float*)d_in[2];
  const float* wv  = (const float*)d_in[3];
  const float* wo  = (const float*)d_in[4];
  const float* qnw = (const float*)d_in[5];
  const float* knw = (const float*)d_in[6];
  float* out = (float*)d_out;

  char* ws = (char*)d_ws;
  u16* qkv = (u16*)(ws);                  // [4096][6144] bf16   50.33 MB
  u16* qr  = (u16*)(ws + 50331648);       // [2][32][2048][128]  33.55 MB
  u16* kr  = (u16*)(ws + 83886080);       // [2][8][2048][128]    8.39 MB
  u16* vt  = (u16*)(ws + 92274688);       // [2][8][128][2048]    8.39 MB
  u16* hsb = (u16*)(ws + 100663296);      // hs bf16             33.55 MB
  u16* wqb = (u16*)(ws + 134217728);      // wq bf16             33.55 MB
  u16* wkb = (u16*)(ws + 167772160);      // wk bf16              8.39 MB
  u16* wvb = (u16*)(ws + 176160768);      // wv bf16              8.39 MB
  u16* ao  = (u16*)(ws);                  // attn out reuses dead qkv region
  u16* wob = qr;                          // wo bf16 reuses dead qr region

  cvt_f32_bf16_k<<<dim3(2048), dim3(256), 0, stream>>>(hs, hsb, 16777216 / 8);
  cvt_f32_bf16_k<<<dim3(2048), dim3(256), 0, stream>>>(wq, wqb, 16777216 / 8);
  cvt_f32_bf16_k<<<dim3(1024), dim3(256), 0, stream>>>(wk, wkb, 4194304 / 8);
  cvt_f32_bf16_k<<<dim3(1024), dim3(256), 0, stream>>>(wv, wvb, 4194304 / 8);

  gemm_bt<0, u16><<<dim3(48, 32), dim3(256), 0, stream>>>(hsb, wqb, wkb, wvb, qkv);
  norm_rope<<<dim3(40960), dim3(256), 0, stream>>>(qkv, qnw, knw, qr, kr);
  transpose_v<<<dim3(32, 16), dim3(256), 0, stream>>>(qkv, vt);
  attn_fwd<<<dim3(16, 64), dim3(256), 0, stream>>>(qr, kr, vt, ao);

  cvt_f32_bf16_k<<<dim3(2048), dim3(256), 0, stream>>>(wo, wob, 16777216 / 8);
  gemm_bt<1, float><<<dim3(32, 32), dim3(256), 0, stream>>>(ao, wob, nullptr, nullptr, out);
}